// Round 9
// baseline (294.821 us; speedup 1.0000x reference)
//
#include <hip/hip_runtime.h>
#include <cstdint>
#include <cstddef>

// ---------------- constants ----------------
#define MAXSEL 160
static constexpr int S    = 4096;
static constexpr int H    = 1024;
static constexpr int DH   = 64;
static constexpr int NB   = 128;   // seq blocks (4096/32)
static constexpr int MBH  = 32;    // b*h = 2*16
static constexpr int M8   = 8192;  // 2*4096 rows
static constexpr int N3   = 3072;  // q|k|v features

typedef _Float16 half8 __attribute__((ext_vector_type(8)));
typedef _Float16 half4v __attribute__((ext_vector_type(4)));
typedef float floatx4 __attribute__((ext_vector_type(4)));

__device__ __forceinline__ void load_lds16(const void* g, void* l) {
  __builtin_amdgcn_global_load_lds((const __attribute__((address_space(1))) unsigned int*)g,
                                   (__attribute__((address_space(3))) unsigned int*)l,
                                   16, 0, 0);
}

// select among 8 register ints without dynamic indexing (rule #20: no scratch)
__device__ __forceinline__ int sel8(int t, int4 a, int4 b) {
  int r = a.x;
  r = (t == 1) ? a.y : r;
  r = (t == 2) ? a.z : r;
  r = (t == 3) ? a.w : r;
  r = (t == 4) ? b.x : r;
  r = (t == 5) ? b.y : r;
  r = (t == 6) ? b.z : r;
  r = (t == 7) ? b.w : r;
  return r;
}

// ---------------- fused prep: hbar + h16 cast | weight cast | selcnt zero -------------
__global__ __launch_bounds__(256) void k_prep(const float* __restrict__ hidden,
                                              const float* __restrict__ am,
                                              const float* __restrict__ wq,
                                              const float* __restrict__ wk,
                                              const float* __restrict__ wv,
                                              _Float16* __restrict__ h16,
                                              _Float16* __restrict__ w16,
                                              _Float16* __restrict__ wlo,
                                              _Float16* __restrict__ hb_hi,
                                              _Float16* __restrict__ hb_lo,
                                              float* __restrict__ tcv,
                                              int* __restrict__ selcnt) {
  const int blk_id = blockIdx.x;
  if (blk_id < 256) {
    if (blk_id == 0) {
      for (int i = threadIdx.x; i < MBH * NB; i += 256) selcnt[i] = 0;
    }
    int b2 = blk_id >> 7, blk = blk_id & 127;
    int c = threadIdx.x * 4;
    float4 s0 = make_float4(0.f, 0.f, 0.f, 0.f);
    float4 s1 = make_float4(0.f, 0.f, 0.f, 0.f);
    for (int i = 0; i < 32; i += 4) {
      int pos0 = blk * 32 + i;
      size_t base = ((size_t)b2 * 4096 + pos0) * 1024 + c;
      const float4 x0 = *(const float4*)&hidden[base];
      const float4 x1 = *(const float4*)&hidden[base + 1024];
      const float4 x2 = *(const float4*)&hidden[base + 2048];
      const float4 x3 = *(const float4*)&hidden[base + 3072];
      float a00 = am[pos0],      a01 = am[pos0 + 1],      a02 = am[pos0 + 2],      a03 = am[pos0 + 3];
      float a10 = am[4096+pos0], a11 = am[4096+pos0 + 1], a12 = am[4096+pos0 + 2], a13 = am[4096+pos0 + 3];
      half4v h;
      h[0]=(_Float16)x0.x; h[1]=(_Float16)x0.y; h[2]=(_Float16)x0.z; h[3]=(_Float16)x0.w;
      *(half4v*)&h16[base] = h;
      h[0]=(_Float16)x1.x; h[1]=(_Float16)x1.y; h[2]=(_Float16)x1.z; h[3]=(_Float16)x1.w;
      *(half4v*)&h16[base + 1024] = h;
      h[0]=(_Float16)x2.x; h[1]=(_Float16)x2.y; h[2]=(_Float16)x2.z; h[3]=(_Float16)x2.w;
      *(half4v*)&h16[base + 2048] = h;
      h[0]=(_Float16)x3.x; h[1]=(_Float16)x3.y; h[2]=(_Float16)x3.z; h[3]=(_Float16)x3.w;
      *(half4v*)&h16[base + 3072] = h;
      float m0, m1;
      m0 = 1.f + a00 * 1e-4f; m1 = 1.f + a10 * 1e-4f;
      s0.x += m0*x0.x; s0.y += m0*x0.y; s0.z += m0*x0.z; s0.w += m0*x0.w;
      s1.x += m1*x0.x; s1.y += m1*x0.y; s1.z += m1*x0.z; s1.w += m1*x0.w;
      m0 = 1.f + a01 * 1e-4f; m1 = 1.f + a11 * 1e-4f;
      s0.x += m0*x1.x; s0.y += m0*x1.y; s0.z += m0*x1.z; s0.w += m0*x1.w;
      s1.x += m1*x1.x; s1.y += m1*x1.y; s1.z += m1*x1.z; s1.w += m1*x1.w;
      m0 = 1.f + a02 * 1e-4f; m1 = 1.f + a12 * 1e-4f;
      s0.x += m0*x2.x; s0.y += m0*x2.y; s0.z += m0*x2.z; s0.w += m0*x2.w;
      s1.x += m1*x2.x; s1.y += m1*x2.y; s1.z += m1*x2.z; s1.w += m1*x2.w;
      m0 = 1.f + a03 * 1e-4f; m1 = 1.f + a13 * 1e-4f;
      s0.x += m0*x3.x; s0.y += m0*x3.y; s0.z += m0*x3.z; s0.w += m0*x3.w;
      s1.x += m1*x3.x; s1.y += m1*x3.y; s1.z += m1*x3.z; s1.w += m1*x3.w;
    }
    size_t row0 = (size_t)(b2 * 2 + 0) * 128 + blk;
    size_t row1 = (size_t)(b2 * 2 + 1) * 128 + blk;
    half4v hi, lo;
    hi[0]=(_Float16)s0.x; lo[0]=(_Float16)(s0.x-(float)hi[0]);
    hi[1]=(_Float16)s0.y; lo[1]=(_Float16)(s0.y-(float)hi[1]);
    hi[2]=(_Float16)s0.z; lo[2]=(_Float16)(s0.z-(float)hi[2]);
    hi[3]=(_Float16)s0.w; lo[3]=(_Float16)(s0.w-(float)hi[3]);
    *(half4v*)&hb_hi[row0 * 1024 + c] = hi;
    *(half4v*)&hb_lo[row0 * 1024 + c] = lo;
    hi[0]=(_Float16)s1.x; lo[0]=(_Float16)(s1.x-(float)hi[0]);
    hi[1]=(_Float16)s1.y; lo[1]=(_Float16)(s1.y-(float)hi[1]);
    hi[2]=(_Float16)s1.z; lo[2]=(_Float16)(s1.z-(float)hi[2]);
    hi[3]=(_Float16)s1.w; lo[3]=(_Float16)(s1.w-(float)hi[3]);
    *(half4v*)&hb_hi[row1 * 1024 + c] = hi;
    *(half4v*)&hb_lo[row1 * 1024 + c] = lo;
    if (b2 == 0 && threadIdx.x == 0) {
      float t0 = 0.f, t1 = 0.f;
      for (int i = 0; i < 32; ++i) {
        int pos = blk * 32 + i;
        t0 += 1.f + am[pos] * 1e-4f;
        t1 += 1.f + am[4096 + pos] * 1e-4f;
      }
      tcv[blk] = t0; tcv[128 + blk] = t1;
    }
  } else {
    long j = (long)(blk_id - 256) * 256 + threadIdx.x;   // float4 index into weights
    const long NW4 = (long)H * H / 4;
    int which = (int)(j / NW4);
    long jj = j - (long)which * NW4;
    const float* src = which == 0 ? wq : (which == 1 ? wk : wv);
    float4 x = ((const float4*)src)[jj];
    half4v h;
    h[0] = (_Float16)x.x; h[1] = (_Float16)x.y;
    h[2] = (_Float16)x.z; h[3] = (_Float16)x.w;
    *(half4v*)&w16[j * 4] = h;
    if (which < 2) {
      half4v r;
      r[0] = (_Float16)(x.x - (float)h[0]);
      r[1] = (_Float16)(x.y - (float)h[1]);
      r[2] = (_Float16)(x.z - (float)h[2]);
      r[3] = (_Float16)(x.w - (float)h[3]);
      *(half4v*)&wlo[j * 4] = r;
    }
  }
}

// ---------------- main QKV projection (R2 config, measured 74us/0-conflict) fused with
// the side GEMM (blocks >= 768; two 256-thr side tiles per 512-thr block) -------------
__global__ __launch_bounds__(512, 4) void k_gemm_qkv(const _Float16* __restrict__ A,
                                                     const _Float16* __restrict__ B,
                                                     const float* __restrict__ bq,
                                                     const float* __restrict__ bk,
                                                     const float* __restrict__ bv,
                                                     const float* __restrict__ am,
                                                     _Float16* __restrict__ q16,
                                                     _Float16* __restrict__ k16,
                                                     _Float16* __restrict__ v16,
                                                     const _Float16* __restrict__ Ahi,
                                                     const _Float16* __restrict__ Alo,
                                                     const _Float16* __restrict__ Blo,
                                                     float* __restrict__ sideQK) {
  __shared__ _Float16 sh[36864];   // 72 KB: gemm As(24K)+Bs(48K) | side 2x 32KB halves

  if (blockIdx.x < 768) {
    // ================= main QKV GEMM (R2, verbatim modulo shared aliasing) ==========
    const int id = blockIdx.x;
    const int swz = (id & 7) * 96 + (id >> 3);   // bijective XCD swizzle
    const int by = swz / 12;          // 0..63  (M tile, 128 rows)
    const int bx = swz - by * 12;     // 0..11  (N tile, 256 cols)
    const int tid = threadIdx.x;
    const int lane = tid & 63, wv = tid >> 6;     // 8 waves
    const int wm = wv >> 2, wn = wv & 3;          // 2 x 4 wave grid
    const int l15 = lane & 15, quad = lane >> 4;

    _Float16* As = sh;           // [3][128*32]
    _Float16* Bs = sh + 12288;   // [3][256*32]

    floatx4 acc[4][4] = {};

    const _Float16* Ag = A + (size_t)(by * 128) * 1024;
    const _Float16* Bg = B + (size_t)(bx * 256) * 1024;

    const int gr  = lane >> 2;                             // row in 16-row window
    const int gcb = ((lane & 3) ^ ((lane >> 3) & 3)) * 8;  // inverse-swizzled src chunk
    const _Float16* agl  = Ag + (size_t)(wv * 16 + gr) * 1024 + gcb;
    const _Float16* bgl0 = Bg + (size_t)(wv * 32 + gr) * 1024 + gcb;
    const _Float16* bgl1 = Bg + (size_t)(wv * 32 + 16 + gr) * 1024 + gcb;
    const int aw  = (wv * 16) * 32;
    const int bw0 = (wv * 32) * 32;
    const int bw1 = (wv * 32 + 16) * 32;

#define STAGE(TT, BB)                                                   \
    {                                                                   \
      load_lds16(agl  + (size_t)(TT) * 32, &As[(BB) * 4096 + aw]);      \
      load_lds16(bgl0 + (size_t)(TT) * 32, &Bs[(BB) * 8192 + bw0]);     \
      load_lds16(bgl1 + (size_t)(TT) * 32, &Bs[(BB) * 8192 + bw1]);     \
    }

    STAGE(0, 0)
    STAGE(1, 1)

    const int rc = ((quad ^ ((l15 >> 1) & 3)) << 3);

#pragma unroll
    for (int t = 0; t < 32; ++t) {
      if (t == 31) { asm volatile("s_waitcnt vmcnt(0)" ::: "memory"); }
      else         { asm volatile("s_waitcnt vmcnt(3)" ::: "memory"); }
      __builtin_amdgcn_s_barrier();
      if (t < 30) {
        const int nb = (t + 2) % 3;
        STAGE(t + 2, nb)
      }
      const int bb = t % 3;
      half8 a[4], b[4];
#pragma unroll
      for (int mt = 0; mt < 4; ++mt)
        a[mt] = *(const half8*)&As[bb * 4096 + (wm * 64 + mt * 16 + l15) * 32 + rc];
#pragma unroll
      for (int nt = 0; nt < 4; ++nt)
        b[nt] = *(const half8*)&Bs[bb * 8192 + (wn * 64 + nt * 16 + l15) * 32 + rc];
      __builtin_amdgcn_s_setprio(1);
#pragma unroll
      for (int mt = 0; mt < 4; ++mt)
#pragma unroll
        for (int nt = 0; nt < 4; ++nt)
          acc[mt][nt] = __builtin_amdgcn_mfma_f32_16x16x32_f16(a[mt], b[nt], acc[mt][nt], 0, 0, 0);
      __builtin_amdgcn_s_setprio(0);
    }
#undef STAGE

    // epilogue: scatter to q16/k16/v16 in (mb, s, dd) layout, + bias, * mask
    const int which = bx >> 2;                 // uniform per CTA (256 | 1024)
    const float* bias = which == 0 ? bq : (which == 1 ? bk : bv);
    _Float16* dst = which == 0 ? q16 : (which == 1 ? k16 : v16);
    const int hh = (bx & 3) * 4 + wn;          // head index, uniform per wave
    const int m2 = hh & 1;
#pragma unroll
    for (int nt = 0; nt < 4; ++nt) {
      const int dd = nt * 16 + l15;
      const float bsv = bias[hh * 64 + dd];
#pragma unroll
      for (int mt = 0; mt < 4; ++mt) {
#pragma unroll
        for (int r = 0; r < 4; ++r) {
          int srow = by * 128 + wm * 64 + mt * 16 + quad * 4 + r;
          int b2 = srow >> 12, s = srow & 4095;
          float mv = 1.f + am[m2 * 4096 + s] * 1e-4f;
          float v = (acc[mt][nt][r] + bsv) * mv;
          int mb = b2 * 16 + hh;
          dst[((size_t)mb * 4096 + s) * 64 + dd] = (_Float16)v;
        }
      }
    }
    return;
  }

  // ================= side GEMM (blocks 768..1023; two 256-thr halves) ===============
  const int half = threadIdx.x >> 8;            // 0 or 1 (wave-aligned split)
  const int stid = threadIdx.x & 255;
  const int sb   = (blockIdx.x - 768) * 2 + half;   // original side block id 0..511
  const int slane = stid & 63, swv = stid >> 6;
  const int kk  = sb >> 8;                      // split-K half
  const int sbb = sb & 255;
  const int sbx = sbb & 31;                     // 0..31 (N/64)
  const int sby = sbb >> 5;                     // 0..7  (M/64)
  const int swm = swv >> 1, swn = swv & 1;
  const int sl15 = slane & 15, squad = slane >> 4;
  _Float16* base = sh + half * 16384;           // 32 KB per half
  _Float16* sAhi = base;
  _Float16* sAlo = base + 4096;
  _Float16* sBhi = base + 8192;
  _Float16* sBlo = base + 12288;

  floatx4 acc[2][2] = {};

  const int srow = slane >> 3;
  const int scol = (((slane & 7) ^ (srow & 7)) * 8);
  const int sswz = sl15 & 7;
  const _Float16* src;
  _Float16* dst;
  if      (swv == 0) { src = Ahi + (size_t)(sby * 64) * 1024; dst = sAhi; }
  else if (swv == 1) { src = Alo + (size_t)(sby * 64) * 1024; dst = sAlo; }
  else if (swv == 2) { src = B   + (size_t)(sbx * 64) * 1024; dst = sBhi; }
  else               { src = Blo + (size_t)(sbx * 64) * 1024; dst = sBlo; }

  const int kbeg = kk * 512;
  for (int k0 = kbeg; k0 < kbeg + 512; k0 += 64) {
    __syncthreads();
#pragma unroll
    for (int i = 0; i < 8; ++i)
      load_lds16(src + (size_t)(i * 8 + srow) * 1024 + k0 + scol, dst + i * 512);
    __syncthreads();
#pragma unroll
    for (int ks = 0; ks < 2; ++ks) {
      const int kc = ks * 4;
      half8 ah[2], al[2], bh[2], bl[2];
#pragma unroll
      for (int mt = 0; mt < 2; ++mt) {
        int off = (swm * 32 + mt * 16 + sl15) * 64 + (((kc + squad) ^ sswz) << 3);
        ah[mt] = *(const half8*)&sAhi[off];
        al[mt] = *(const half8*)&sAlo[off];
      }
#pragma unroll
      for (int nt = 0; nt < 2; ++nt) {
        int off = (swn * 32 + nt * 16 + sl15) * 64 + (((kc + squad) ^ sswz) << 3);
        bh[nt] = *(const half8*)&sBhi[off];
        bl[nt] = *(const half8*)&sBlo[off];
      }
#pragma unroll
      for (int mt = 0; mt < 2; ++mt)
#pragma unroll
        for (int nt = 0; nt < 2; ++nt) {
          acc[mt][nt] = __builtin_amdgcn_mfma_f32_16x16x32_f16(ah[mt], bh[nt], acc[mt][nt], 0, 0, 0);
          acc[mt][nt] = __builtin_amdgcn_mfma_f32_16x16x32_f16(ah[mt], bl[nt], acc[mt][nt], 0, 0, 0);
          acc[mt][nt] = __builtin_amdgcn_mfma_f32_16x16x32_f16(al[mt], bh[nt], acc[mt][nt], 0, 0, 0);
        }
    }
  }
  float* outp = sideQK + (size_t)kk * (512 * 2048);
#pragma unroll
  for (int mt = 0; mt < 2; ++mt)
#pragma unroll
    for (int nt = 0; nt < 2; ++nt)
#pragma unroll
      for (int rr = 0; rr < 4; ++rr) {
        int row = sby * 64 + swm * 32 + mt * 16 + squad * 4 + rr;
        int col = sbx * 64 + swn * 32 + nt * 16 + sl15;
        outp[(size_t)row * 2048 + col] = acc[mt][nt][rr];
      }
}

// ---------------- low-resolution logits + row max | vprep (blocks >= 256) ------------
// vprep writes v16T in (mb, kb, d, s) block-d-major layout: each k_hi V-fragment load
// covers 16 full 64B lines.
__global__ __launch_bounds__(256) void k_lowlogit(const float* __restrict__ sideQK,
                                                  const float* __restrict__ tcv,
                                                  const float* __restrict__ bq,
                                                  const float* __restrict__ bk,
                                                  float* __restrict__ ll,
                                                  float* __restrict__ rmaxout,
                                                  const _Float16* __restrict__ v16,
                                                  float* __restrict__ vhat,
                                                  _Float16* __restrict__ v16T) {
  __shared__ __attribute__((aligned(16))) char shraw[37376];
  const int tid = threadIdx.x;

  if (blockIdx.x >= 256) {
    // ---- vprep: one wave per (mb, blk) ----
    const int lane = tid & 63, wv = tid >> 6;
    _Float16* Vs = (_Float16*)shraw + wv * 2304;   // 32*72
    int bid = (blockIdx.x - 256) * 4 + wv;         // 0..4095
    int mb = bid >> 7, blk = bid & 127;
    const _Float16* src = v16 + ((size_t)mb * 4096 + blk * 32) * 64;
    int r = lane >> 3, c = (lane & 7) * 8;
#pragma unroll
    for (int it = 0; it < 4; ++it)
      *(uint4*)&Vs[(it * 8 + r) * 72 + c] = *(const uint4*)&src[(it * 8 + r) * 64 + c];
    __syncthreads();
    float acc = 0.f;
    half8 col[4];
#pragma unroll
    for (int k = 0; k < 32; ++k) {
      _Float16 x = Vs[k * 72 + lane];
      col[k >> 3][k & 7] = x;
      acc += (float)x;
    }
    vhat[(size_t)bid * 64 + lane] = acc / (tcv[(mb & 1) * 128 + blk] + 1e-6f);
    // (mb, kb, d, s): lane = d owns one contiguous 64B row of 32 k-entries
    _Float16* dst = v16T + ((size_t)(mb * 128 + blk) * 64 + lane) * 32;
#pragma unroll
    for (int p = 0; p < 4; ++p) *(half8*)&dst[p * 8] = col[p];
    return;
  }

  const int mb = blockIdx.x >> 3;
  const int ib = blockIdx.x & 7;       // 0..7 : rows ib*16..+16
  const int b2 = mb >> 4, m2 = mb & 1, hh = mb & 15;
  const int combo = b2 * 2 + m2;
  float* Kh  = (float*)shraw;                     // 128*64
  float* Qh  = (float*)(shraw + 32768);           // 16*64
  float* tcL = (float*)(shraw + 32768 + 4096);    // 128

  const float* P1 = sideQK + (size_t)512 * 2048;

  if (tid < 128) tcL[tid] = tcv[m2 * 128 + tid];
  __syncthreads();
#pragma unroll
  for (int i = 0; i < 8; ++i) {
    int ci = tid + i * 256;
    int row = ci >> 4, c4 = (ci & 15) * 4;
    float tck = tcL[row];
    float den = 1.f / (tck + 1e-6f);
    size_t idx = ((size_t)combo * 128 + row) * 2048 + 1024 + hh * 64 + c4;
    float4 x0 = *(const float4*)&sideQK[idx];
    float4 x1 = *(const float4*)&P1[idx];
    float4 bb = *(const float4*)&bk[hh * 64 + c4];
    float4 o;
    o.x = (x0.x + x1.x + bb.x * tck) * den; o.y = (x0.y + x1.y + bb.y * tck) * den;
    o.z = (x0.z + x1.z + bb.z * tck) * den; o.w = (x0.w + x1.w + bb.w * tck) * den;
    *(float4*)&Kh[row * 64 + c4] = o;
  }
  {
    int row = tid >> 4, c4 = (tid & 15) * 4;
    int gi = ib * 16 + row;
    float tcq = tcL[gi];
    float den = 1.f / (tcq + 1e-6f);
    size_t idx = ((size_t)combo * 128 + gi) * 2048 + hh * 64 + c4;
    float4 x0 = *(const float4*)&sideQK[idx];
    float4 x1 = *(const float4*)&P1[idx];
    float4 bb = *(const float4*)&bq[hh * 64 + c4];
    float4 o;
    o.x = (x0.x + x1.x + bb.x * tcq) * den; o.y = (x0.y + x1.y + bb.y * tcq) * den;
    o.z = (x0.z + x1.z + bb.z * tcq) * den; o.w = (x0.w + x1.w + bb.w * tcq) * den;
    *(float4*)&Qh[row * 64 + c4] = o;
  }
  __syncthreads();

  const int il = tid >> 4, jg = tid & 15;
  const int i = ib * 16 + il;
  float tcq = tcL[i];
  float dots[8] = {};
#pragma unroll
  for (int dd = 0; dd < 16; ++dd) {
    int d4 = ((dd + tid) & 15) * 4;       // lane-rotated: conflict-free LDS columns
    float4 qv = *(const float4*)&Qh[il * 64 + d4];
#pragma unroll
    for (int jj = 0; jj < 8; ++jj) {
      float4 kv = *(const float4*)&Kh[(jg * 8 + jj) * 64 + d4];
      dots[jj] += qv.x * kv.x + qv.y * kv.y + qv.z * kv.z + qv.w * kv.w;
    }
  }
  float tmax = -1e30f;
#pragma unroll
  for (int jj = 0; jj < 8; ++jj) {
    int j = jg * 8 + jj;
    float raw = dots[jj] * 0.125f;
    tmax = fmaxf(tmax, raw);
    float pen = (tcq * tcL[j] < 0.5f) ? 10000.f : 0.f;
    ll[(size_t)mb * 16384 + (size_t)i * 128 + j] = raw - pen;
  }
#pragma unroll
  for (int mk = 1; mk < 16; mk <<= 1) tmax = fmaxf(tmax, __shfl_xor(tmax, mk));
  if (jg == 0) rmaxout[mb * 128 + i] = tmax;
}

// ---------------- exact top-512 threshold + selected-block buckets --------------------
__global__ __launch_bounds__(256) void k_topk(const float* __restrict__ ll,
                                              const float* __restrict__ rmax,
                                              float* __restrict__ thr,
                                              int* __restrict__ selcnt,
                                              int* __restrict__ selkb) {
  const int mb = blockIdx.x;
  const int t = threadIdx.x;
  const int wid = t >> 6;
  __shared__ int red2[2][4];

  unsigned code[64];
#pragma unroll
  for (int j = 0; j < 64; ++j) {
    int e = j * 256 + t;
    int i = e >> 7, jj = e & 127;
    float lrn = ll[(size_t)mb * 16384 + e] - rmax[mb * 128 + i];
    int di = i - jj;
    if (di <= 1 && di >= -1) lrn += 5000.f;
    unsigned b = __float_as_uint(lrn);
    code[j] = (b & 0x80000000u) ? ~b : (b | 0x80000000u);
  }

  unsigned lo = 0u, hi = 0xFFFFFFFFu;
  for (int it = 0; it < 32; ++it) {
    unsigned mid = lo + ((hi - lo) >> 1);
    int c = 0;
#pragma unroll
    for (int j = 0; j < 64; ++j) c += (code[j] >= mid) ? 1 : 0;
#pragma unroll
    for (int mk = 1; mk < 64; mk <<= 1) c += __shfl_xor(c, mk);
    if ((t & 63) == 0) red2[it & 1][wid] = c;
    __syncthreads();
    int total = red2[it & 1][0] + red2[it & 1][1] + red2[it & 1][2] + red2[it & 1][3];
    if (total >= 512) lo = mid; else hi = mid;
  }
  if (t == 0) {
    unsigned bits = (lo & 0x80000000u) ? (lo & 0x7FFFFFFFu) : ~lo;
    thr[mb] = __uint_as_float(bits);
  }
#pragma unroll
  for (int j = 0; j < 64; ++j) {
    if (code[j] >= lo) {
      int e = j * 256 + t;
      int i = e >> 7, jj = e & 127;
      int slot = atomicAdd(&selcnt[mb * 128 + i], 1);
      if (slot < MAXSEL) selkb[(size_t)(mb * 128 + i) * MAXSEL + slot] = jj;
    }
  }
}

// ---------------- hi branch: 2-wave tail-split online softmax + LDS merge -------------
// 128 thr per (mb,qb). Wave w runs the R8 trip body over t = w, w+2, ... with its own
// online state (flash split); low branch split j in [w*64,+64). One barrier; wave 0
// merges the single published state (R6-verified math) and writes output.
// Occupancy: ~17.8 KB LDS + ~96 VGPR -> 8 blocks/CU (vs R6's 3) -> tail halves.
__global__ __launch_bounds__(128) void k_hi(const _Float16* __restrict__ q16,
                                            const _Float16* __restrict__ k16,
                                            const _Float16* __restrict__ v16T,
                                            const int* __restrict__ selcnt,
                                            const int* __restrict__ selkb,
                                            const float* __restrict__ rmax,
                                            const float* __restrict__ thr,
                                            const float* __restrict__ tcv,
                                            const float* __restrict__ vhat,
                                            const float* __restrict__ ll,
                                            const float* __restrict__ am,
                                            float* __restrict__ out) {
  const int mb = blockIdx.x & 31, qb = blockIdx.x >> 5;
  const int sid = mb * 128 + qb;
  const int tid = threadIdx.x;
  const int lane = tid & 63, wid = tid >> 6;    // 2 waves
  const int l15 = lane & 15, quad = lane >> 4;
  const int m2 = mb & 1, b2 = mb >> 4, hh = mb & 15;

  __shared__ _Float16 Ps[2][32 * 40];   // per-wave P staging (5 KB)
  __shared__ float mrg[64][50];         // merge state, stride 50 (2-way alias = free)

  const _Float16* qbase = q16 + ((size_t)mb * 4096 + qb * 32) * 64;
  half8 aq[2][2];
#pragma unroll
  for (int mt = 0; mt < 2; ++mt)
#pragma unroll
    for (int ks = 0; ks < 2; ++ks)
      aq[mt][ks] = *(const half8*)&qbase[(mt * 16 + l15) * 64 + ks * 32 + quad * 8];

  // prefetch selected-block ids 0..7 (list contiguous, MAXSEL capacity -> safe)
  const int* list = selkb + (size_t)sid * MAXSEL;
  const int4 La = *(const int4*)&list[0];
  const int4 Lb = *(const int4*)&list[4];

  // ---- low branch partial: wave w covers j in [w*64, w*64+64); MLP accumulators ----
  const float rmaxb = rmax[sid];
  const float th = thr[mb];
  const float* llrow = ll + (size_t)mb * 16384 + (size_t)qb * 128;
  const float* tcrow = tcv + m2 * 128;
  const float* vhbase = vhat + ((size_t)(mb * 128)) * 64 + lane;
  float a0 = 0.f, a1 = 0.f, a2 = 0.f, a3 = 0.f;
  float n0 = 0.f, n1 = 0.f, n2 = 0.f, n3 = 0.f;
#pragma unroll 2
  for (int j0 = wid * 64; j0 < wid * 64 + 64; j0 += 4) {
    float4 l4 = *(const float4*)&llrow[j0];
    float4 t4 = *(const float4*)&tcrow[j0];
    float v0 = vhbase[(size_t)(j0 + 0) * 64];
    float v1 = vhbase[(size_t)(j0 + 1) * 64];
    float v2 = vhbase[(size_t)(j0 + 2) * 64];
    float v3 = vhbase[(size_t)(j0 + 3) * 64];
    int d0 = qb - j0;
    float lr0 = l4.x - rmaxb + ((d0 <= 1 && d0 >= -1) ? 5000.f : 0.f);
    float lr1 = l4.y - rmaxb + ((d0 <= 2 && d0 >= 0) ? 5000.f : 0.f);
    float lr2 = l4.z - rmaxb + ((d0 <= 3 && d0 >= 1) ? 5000.f : 0.f);
    float lr3 = l4.w - rmaxb + ((d0 <= 4 && d0 >= 2) ? 5000.f : 0.f);
    float w0 = (lr0 >= th) ? 0.f : __expf(l4.x - rmaxb) * t4.x;
    float w1 = (lr1 >= th) ? 0.f : __expf(l4.y - rmaxb) * t4.y;
    float w2 = (lr2 >= th) ? 0.f : __expf(l4.z - rmaxb) * t4.z;
    float w3 = (lr3 >= th) ? 0.f : __expf(l4.w - rmaxb) * t4.w;
    a0 += w0 * v0; a1 += w1 * v1; a2 += w2 * v2; a3 += w3 * v3;
    n0 += w0; n1 += w1; n2 += w2; n3 += w3;
  }
  float accL = (a0 + a1) + (a2 + a3);
  float nrmL = (n0 + n1) + (n2 + n3);

  int nk = selcnt[sid];
  if (nk > MAXSEL) nk = MAXSEL;

  const _Float16* kbase  = k16  + (size_t)mb * 4096 * 64;
  const _Float16* vtbase = v16T + (size_t)mb * 128 * 2048;

  float rm[2][4];
  floatx4 o[2][4] = {};
  floatx4 onrm[2] = {};
#pragma unroll
  for (int mt = 0; mt < 2; ++mt)
#pragma unroll
    for (int r = 0; r < 4; ++r) rm[mt][r] = -1e8f;

  half8 ones;
#pragma unroll
  for (int j = 0; j < 8; ++j) ones[j] = (_Float16)1.f;

  _Float16* myPs = &Ps[wid][0];

  for (int t = wid; t < nk; t += 2) {
    const int kb = (t < 8) ? sel8(t, La, Lb) : list[t];
    const _Float16* kp = kbase + (size_t)kb * 32 * 64;
    half8 b0[2], b1[2];
#pragma unroll
    for (int ks = 0; ks < 2; ++ks) {
      b0[ks] = *(const half8*)&kp[(l15) * 64 + ks * 32 + quad * 8];
      b1[ks] = *(const half8*)&kp[(16 + l15) * 64 + ks * 32 + quad * 8];
    }
    // V fragments, (mb, kb, d, s) layout: 16 full 64B lines per load instruction
    const _Float16* vp = vtbase + kb * 2048 + quad * 8;
    half8 vb0 = *(const half8*)&vp[(l15) * 32];
    half8 vb1 = *(const half8*)&vp[(16 + l15) * 32];
    half8 vb2 = *(const half8*)&vp[(32 + l15) * 32];
    half8 vb3 = *(const half8*)&vp[(48 + l15) * 32];

    floatx4 sf[2][2] = {};
    sf[0][0] = __builtin_amdgcn_mfma_f32_16x16x32_f16(aq[0][0], b0[0], sf[0][0], 0, 0, 0);
    sf[0][0] = __builtin_amdgcn_mfma_f32_16x16x32_f16(aq[0][1], b0[1], sf[0][0], 0, 0, 0);
    sf[0][1] = __builtin_amdgcn_mfma_f32_16x16x32_f16(aq[0][0], b1[0], sf[0][1], 0, 0, 0);
    sf[0][1] = __builtin_amdgcn_mfma_f32_16x16x32_f16(aq[0][1], b1[1], sf[0][1], 0, 0, 0);
    sf[1][0] = __builtin_amdgcn_mfma_f32_16x16x32_f16(aq[1][0], b0[0], sf[1][0], 0, 0, 0);
    sf[1][0] = __builtin_amdgcn_mfma_f32_16x16x32_f16(aq[1][1], b0[1], sf[1][0], 0, 0, 0);
    sf[1][1] = __builtin_amdgcn_mfma_f32_16x16x32_f16(aq[1][0], b1[0], sf[1][1], 0, 0, 0);
    sf[1][1] = __builtin_amdgcn_mfma_f32_16x16x32_f16(aq[1][1], b1[1], sf[1][1], 0, 0, 0);

    float pen0, pen1;
    {
      float mk0 = 1.f + am[m2 * 4096 + kb * 32 + l15] * 1e-4f;
      float mk1 = 1.f + am[m2 * 4096 + kb * 32 + 16 + l15] * 1e-4f;
      pen0 = 10000.f * (1.f - mk0);
      pen1 = 10000.f * (1.f - mk1);
    }
#pragma unroll
    for (int mt = 0; mt < 2; ++mt)
#pragma unroll
      for (int r = 0; r < 4; ++r) {
        float s0 = sf[mt][0][r] * 0.125f;
        float s1 = sf[mt][1][r] * 0.125f;
        float v = fmaxf(s0, s1);
#pragma unroll
        for (int mk = 1; mk < 16; mk <<= 1) v = fmaxf(v, __shfl_xor(v, mk));
        float mnew  = fmaxf(rm[mt][r], v);
        float alpha = __expf(rm[mt][r] - mnew);
        rm[mt][r] = mnew;
        float p0 = __expf(s0 - mnew - pen0);
        float p1 = __expf(s1 - mnew - pen1);
        o[mt][0][r] *= alpha; o[mt][1][r] *= alpha;
        o[mt][2][r] *= alpha; o[mt][3][r] *= alpha;
        onrm[mt][r] *= alpha;
        int row = mt * 16 + quad * 4 + r;
        myPs[row * 40 + l15] = (_Float16)p0;
        myPs[row * 40 + 16 + l15] = (_Float16)p1;
      }
    // per-wave Ps: DS in-order per wave; wait for P writes, then read (no barrier)
    __builtin_amdgcn_sched_barrier(0);
    asm volatile("s_waitcnt lgkmcnt(0)" ::: "memory");
    __builtin_amdgcn_sched_barrier(0);
    half8 pa0 = *(const half8*)&myPs[(l15) * 40 + quad * 8];
    half8 pa1 = *(const half8*)&myPs[(16 + l15) * 40 + quad * 8];
    o[0][0] = __builtin_amdgcn_mfma_f32_16x16x32_f16(pa0, vb0, o[0][0], 0, 0, 0);
    o[0][1] = __builtin_amdgcn_mfma_f32_16x16x32_f16(pa0, vb1, o[0][1], 0, 0, 0);
    o[0][2] = __builtin_amdgcn_mfma_f32_16x16x32_f16(pa0, vb2, o[0][2], 0, 0, 0);
    o[0][3] = __builtin_amdgcn_mfma_f32_16x16x32_f16(pa0, vb3, o[0][3], 0, 0, 0);
    o[1][0] = __builtin_amdgcn_mfma_f32_16x16x32_f16(pa1, vb0, o[1][0], 0, 0, 0);
    o[1][1] = __builtin_amdgcn_mfma_f32_16x16x32_f16(pa1, vb1, o[1][1], 0, 0, 0);
    o[1][2] = __builtin_amdgcn_mfma_f32_16x16x32_f16(pa1, vb2, o[1][2], 0, 0, 0);
    o[1][3] = __builtin_amdgcn_mfma_f32_16x16x32_f16(pa1, vb3, o[1][3], 0, 0, 0);
    onrm[0] = __builtin_amdgcn_mfma_f32_16x16x32_f16(pa0, ones, onrm[0], 0, 0, 0);
    onrm[1] = __builtin_amdgcn_mfma_f32_16x16x32_f16(pa1, ones, onrm[1], 0, 0, 0);
  }

  // ---- publish state (wave 1), merge + combine + write (wave 0) ----
  if (wid == 1) {
    float* st = &mrg[lane][0];
#pragma unroll
    for (int mt = 0; mt < 2; ++mt)
#pragma unroll
      for (int r = 0; r < 4; ++r) {
#pragma unroll
        for (int ntd = 0; ntd < 4; ++ntd) st[mt * 16 + ntd * 4 + r] = o[mt][ntd][r];
        st[32 + mt * 4 + r] = onrm[mt][r];
        st[40 + mt * 4 + r] = rm[mt][r];
      }
    st[48] = accL;
    st[49] = nrmL;
  }
  __syncthreads();
  if (wid != 0) return;

  {
    const float* st = &mrg[lane][0];
    accL += st[48];
    nrmL += st[49];
#pragma unroll
    for (int mt = 0; mt < 2; ++mt)
#pragma unroll
      for (int r = 0; r < 4; ++r) {
        float rmw = st[40 + mt * 4 + r];
        float mnew = fmaxf(rm[mt][r], rmw);
        float g0 = __expf(rm[mt][r] - mnew);
        float g1 = __expf(rmw - mnew);
        rm[mt][r] = mnew;
#pragma unroll
        for (int ntd = 0; ntd < 4; ++ntd)
          o[mt][ntd][r] = o[mt][ntd][r] * g0 + st[mt * 16 + ntd * 4 + r] * g1;
        onrm[mt][r] = onrm[mt][r] * g0 + st[32 + mt * 4 + r] * g1;
      }
  }

  // ---- combine with low branch and write output ----
  float lo_d[4];
#pragma unroll
  for (int ntd = 0; ntd < 4; ++ntd) lo_d[ntd] = __shfl(accL, ntd * 16 + l15);
#pragma unroll
  for (int mt = 0; mt < 2; ++mt) {
#pragma unroll
    for (int r = 0; r < 4; ++r) {
      int q = mt * 16 + quad * 4 + r;
      int qpos = qb * 32 + q;
      float mq = 1.f + am[m2 * 4096 + qpos] * 1e-4f;
      float logc = (rmaxb - rm[mt][r]) * mq;
      float lc = __expf(fminf(logc, 0.f));
      float hc = __expf(-fmaxf(logc, 0.f));
      float den = onrm[mt][r] * hc + nrmL * lc + 1e-6f;
      float sc = mq / den;
#pragma unroll
      for (int ntd = 0; ntd < 4; ++ntd) {
        float val = (o[mt][ntd][r] * hc + lo_d[ntd] * lc) * sc;
        out[((size_t)b2 * 4096 + qpos) * 1024 + hh * 64 + ntd * 16 + l15] = val;
      }
    }
  }
}

// ---------------- host launch ----------------
extern "C" void kernel_launch(void* const* d_in, const int* in_sizes, int n_in,
                              void* d_out, int out_size, void* d_ws, size_t ws_size,
                              hipStream_t stream) {
  const float* hidden = (const float*)d_in[0];
  const float* am     = (const float*)d_in[1];
  const float* wq     = (const float*)d_in[2];
  const float* bq     = (const float*)d_in[3];
  const float* wk     = (const float*)d_in[4];
  const float* bk     = (const float*)d_in[5];
  const float* wv     = (const float*)d_in[6];
  const float* bv     = (const float*)d_in[7];
  float* out = (float*)d_out;

  char* ws = (char*)d_ws;
  size_t off = 0;
  auto alloc = [&](size_t bytes) -> char* {
    char* p = ws + off;
    off += (bytes + 255) & ~(size_t)255;
    return p;
  };
  _Float16* h16    = (_Float16*)alloc((size_t)M8 * H * 2);      // aliased by v16T later
  _Float16* w16    = (_Float16*)alloc((size_t)N3 * H * 2);
  _Float16* wlo    = (_Float16*)alloc((size_t)2 * H * H * 2);
  _Float16* q16    = (_Float16*)alloc((size_t)MBH * S * DH * 2);
  _Float16* k16    = (_Float16*)alloc((size_t)MBH * S * DH * 2);
  _Float16* v16    = (_Float16*)alloc((size_t)MBH * S * DH * 2);
  _Float16* hb_hi  = (_Float16*)alloc((size_t)4 * NB * H * 2);
  _Float16* hb_lo  = (_Float16*)alloc((size_t)4 * NB * H * 2);
  float* tcv       = (float*)alloc((size_t)2 * NB * 4);
  float* sideQK    = (float*)alloc((size_t)2 * 512 * 2048 * 4);  // 2 split-K partials
  float* ll        = (float*)alloc((size_t)MBH * NB * NB * 4);
  float* rmax      = (float*)alloc((size_t)MBH * NB * 4);
  float* thr       = (float*)alloc((size_t)MBH * 4);
  int*   selcnt    = (int*)alloc((size_t)MBH * NB * 4);
  int*   selkb     = (int*)alloc((size_t)MBH * NB * MAXSEL * 4);
  float* vhat      = (float*)alloc((size_t)MBH * NB * DH * 4);
  _Float16* v16T   = h16;   // h16 dead after k_gemm_qkv; same element count (8.4M)

  k_prep<<<dim3(3328), dim3(256), 0, stream>>>(hidden, am, wq, wk, wv,
                                               h16, w16, wlo, hb_hi, hb_lo, tcv, selcnt);
  // fused: main QKV GEMM (blocks 0..767) + side GEMM (blocks 768..1023)
  k_gemm_qkv<<<dim3(1024), dim3(512), 0, stream>>>(h16, w16, bq, bk, bv, am,
                                                   q16, k16, v16,
                                                   hb_hi, hb_lo, wlo, sideQK);
  // fused: low-res logits (blocks 0..255) + V prep (blocks 256..1279)
  k_lowlogit<<<dim3(1280), dim3(256), 0, stream>>>(sideQK, tcv, bq, bk, ll, rmax,
                                                   v16, vhat, v16T);
  k_topk<<<dim3(32), dim3(256), 0, stream>>>(ll, rmax, thr, selcnt, selkb);
  k_hi<<<dim3(4096), dim3(128), 0, stream>>>(q16, k16, v16T, selcnt, selkb, rmax, thr,
                                             tcv, vhat, ll, am, out);
}

// Round 10
// 274.563 us; speedup vs baseline: 1.0738x; 1.0738x over previous
//
#include <hip/hip_runtime.h>
#include <cstdint>
#include <cstddef>

// ---------------- constants ----------------
#define MAXSEL 160
static constexpr int S    = 4096;
static constexpr int H    = 1024;
static constexpr int DH   = 64;
static constexpr int NB   = 128;   // seq blocks (4096/32)
static constexpr int MBH  = 32;    // b*h = 2*16
static constexpr int M8   = 8192;  // 2*4096 rows
static constexpr int N3   = 3072;  // q|k|v features

typedef _Float16 half8 __attribute__((ext_vector_type(8)));
typedef _Float16 half4v __attribute__((ext_vector_type(4)));
typedef float floatx4 __attribute__((ext_vector_type(4)));

__device__ __forceinline__ void load_lds16(const void* g, void* l) {
  __builtin_amdgcn_global_load_lds((const __attribute__((address_space(1))) unsigned int*)g,
                                   (__attribute__((address_space(3))) unsigned int*)l,
                                   16, 0, 0);
}

// select among 8 register ints without dynamic indexing (rule #20: no scratch)
__device__ __forceinline__ int sel8(int t, int4 a, int4 b) {
  int r = a.x;
  r = (t == 1) ? a.y : r;
  r = (t == 2) ? a.z : r;
  r = (t == 3) ? a.w : r;
  r = (t == 4) ? b.x : r;
  r = (t == 5) ? b.y : r;
  r = (t == 6) ? b.z : r;
  r = (t == 7) ? b.w : r;
  return r;
}

// ---------------- fused prep: hbar + h16 cast | weight cast | selcnt zero -------------
__global__ __launch_bounds__(256) void k_prep(const float* __restrict__ hidden,
                                              const float* __restrict__ am,
                                              const float* __restrict__ wq,
                                              const float* __restrict__ wk,
                                              const float* __restrict__ wv,
                                              _Float16* __restrict__ h16,
                                              _Float16* __restrict__ w16,
                                              _Float16* __restrict__ wlo,
                                              _Float16* __restrict__ hb_hi,
                                              _Float16* __restrict__ hb_lo,
                                              float* __restrict__ tcv,
                                              int* __restrict__ selcnt) {
  const int blk_id = blockIdx.x;
  if (blk_id < 256) {
    if (blk_id == 0) {
      for (int i = threadIdx.x; i < MBH * NB; i += 256) selcnt[i] = 0;
    }
    int b2 = blk_id >> 7, blk = blk_id & 127;
    int c = threadIdx.x * 4;
    float4 s0 = make_float4(0.f, 0.f, 0.f, 0.f);
    float4 s1 = make_float4(0.f, 0.f, 0.f, 0.f);
    for (int i = 0; i < 32; i += 4) {
      int pos0 = blk * 32 + i;
      size_t base = ((size_t)b2 * 4096 + pos0) * 1024 + c;
      const float4 x0 = *(const float4*)&hidden[base];
      const float4 x1 = *(const float4*)&hidden[base + 1024];
      const float4 x2 = *(const float4*)&hidden[base + 2048];
      const float4 x3 = *(const float4*)&hidden[base + 3072];
      float a00 = am[pos0],      a01 = am[pos0 + 1],      a02 = am[pos0 + 2],      a03 = am[pos0 + 3];
      float a10 = am[4096+pos0], a11 = am[4096+pos0 + 1], a12 = am[4096+pos0 + 2], a13 = am[4096+pos0 + 3];
      half4v h;
      h[0]=(_Float16)x0.x; h[1]=(_Float16)x0.y; h[2]=(_Float16)x0.z; h[3]=(_Float16)x0.w;
      *(half4v*)&h16[base] = h;
      h[0]=(_Float16)x1.x; h[1]=(_Float16)x1.y; h[2]=(_Float16)x1.z; h[3]=(_Float16)x1.w;
      *(half4v*)&h16[base + 1024] = h;
      h[0]=(_Float16)x2.x; h[1]=(_Float16)x2.y; h[2]=(_Float16)x2.z; h[3]=(_Float16)x2.w;
      *(half4v*)&h16[base + 2048] = h;
      h[0]=(_Float16)x3.x; h[1]=(_Float16)x3.y; h[2]=(_Float16)x3.z; h[3]=(_Float16)x3.w;
      *(half4v*)&h16[base + 3072] = h;
      float m0, m1;
      m0 = 1.f + a00 * 1e-4f; m1 = 1.f + a10 * 1e-4f;
      s0.x += m0*x0.x; s0.y += m0*x0.y; s0.z += m0*x0.z; s0.w += m0*x0.w;
      s1.x += m1*x0.x; s1.y += m1*x0.y; s1.z += m1*x0.z; s1.w += m1*x0.w;
      m0 = 1.f + a01 * 1e-4f; m1 = 1.f + a11 * 1e-4f;
      s0.x += m0*x1.x; s0.y += m0*x1.y; s0.z += m0*x1.z; s0.w += m0*x1.w;
      s1.x += m1*x1.x; s1.y += m1*x1.y; s1.z += m1*x1.z; s1.w += m1*x1.w;
      m0 = 1.f + a02 * 1e-4f; m1 = 1.f + a12 * 1e-4f;
      s0.x += m0*x2.x; s0.y += m0*x2.y; s0.z += m0*x2.z; s0.w += m0*x2.w;
      s1.x += m1*x2.x; s1.y += m1*x2.y; s1.z += m1*x2.z; s1.w += m1*x2.w;
      m0 = 1.f + a03 * 1e-4f; m1 = 1.f + a13 * 1e-4f;
      s0.x += m0*x3.x; s0.y += m0*x3.y; s0.z += m0*x3.z; s0.w += m0*x3.w;
      s1.x += m1*x3.x; s1.y += m1*x3.y; s1.z += m1*x3.z; s1.w += m1*x3.w;
    }
    size_t row0 = (size_t)(b2 * 2 + 0) * 128 + blk;
    size_t row1 = (size_t)(b2 * 2 + 1) * 128 + blk;
    half4v hi, lo;
    hi[0]=(_Float16)s0.x; lo[0]=(_Float16)(s0.x-(float)hi[0]);
    hi[1]=(_Float16)s0.y; lo[1]=(_Float16)(s0.y-(float)hi[1]);
    hi[2]=(_Float16)s0.z; lo[2]=(_Float16)(s0.z-(float)hi[2]);
    hi[3]=(_Float16)s0.w; lo[3]=(_Float16)(s0.w-(float)hi[3]);
    *(half4v*)&hb_hi[row0 * 1024 + c] = hi;
    *(half4v*)&hb_lo[row0 * 1024 + c] = lo;
    hi[0]=(_Float16)s1.x; lo[0]=(_Float16)(s1.x-(float)hi[0]);
    hi[1]=(_Float16)s1.y; lo[1]=(_Float16)(s1.y-(float)hi[1]);
    hi[2]=(_Float16)s1.z; lo[2]=(_Float16)(s1.z-(float)hi[2]);
    hi[3]=(_Float16)s1.w; lo[3]=(_Float16)(s1.w-(float)hi[3]);
    *(half4v*)&hb_hi[row1 * 1024 + c] = hi;
    *(half4v*)&hb_lo[row1 * 1024 + c] = lo;
    if (b2 == 0 && threadIdx.x == 0) {
      float t0 = 0.f, t1 = 0.f;
      for (int i = 0; i < 32; ++i) {
        int pos = blk * 32 + i;
        t0 += 1.f + am[pos] * 1e-4f;
        t1 += 1.f + am[4096 + pos] * 1e-4f;
      }
      tcv[blk] = t0; tcv[128 + blk] = t1;
    }
  } else {
    long j = (long)(blk_id - 256) * 256 + threadIdx.x;   // float4 index into weights
    const long NW4 = (long)H * H / 4;
    int which = (int)(j / NW4);
    long jj = j - (long)which * NW4;
    const float* src = which == 0 ? wq : (which == 1 ? wk : wv);
    float4 x = ((const float4*)src)[jj];
    half4v h;
    h[0] = (_Float16)x.x; h[1] = (_Float16)x.y;
    h[2] = (_Float16)x.z; h[3] = (_Float16)x.w;
    *(half4v*)&w16[j * 4] = h;
    if (which < 2) {
      half4v r;
      r[0] = (_Float16)(x.x - (float)h[0]);
      r[1] = (_Float16)(x.y - (float)h[1]);
      r[2] = (_Float16)(x.z - (float)h[2]);
      r[3] = (_Float16)(x.w - (float)h[3]);
      *(half4v*)&wlo[j * 4] = r;
    }
  }
}

// ---------------- main QKV projection (R2 config, measured 74us/0-conflict) fused with
// the side GEMM (blocks >= 768; two 256-thr side tiles per 512-thr block) -------------
__global__ __launch_bounds__(512, 4) void k_gemm_qkv(const _Float16* __restrict__ A,
                                                     const _Float16* __restrict__ B,
                                                     const float* __restrict__ bq,
                                                     const float* __restrict__ bk,
                                                     const float* __restrict__ bv,
                                                     const float* __restrict__ am,
                                                     _Float16* __restrict__ q16,
                                                     _Float16* __restrict__ k16,
                                                     _Float16* __restrict__ v16,
                                                     const _Float16* __restrict__ Ahi,
                                                     const _Float16* __restrict__ Alo,
                                                     const _Float16* __restrict__ Blo,
                                                     float* __restrict__ sideQK) {
  __shared__ _Float16 sh[36864];   // 72 KB: gemm As(24K)+Bs(48K) | side 2x 32KB halves

  if (blockIdx.x < 768) {
    // ================= main QKV GEMM (R2, verbatim modulo shared aliasing) ==========
    const int id = blockIdx.x;
    const int swz = (id & 7) * 96 + (id >> 3);   // bijective XCD swizzle
    const int by = swz / 12;          // 0..63  (M tile, 128 rows)
    const int bx = swz - by * 12;     // 0..11  (N tile, 256 cols)
    const int tid = threadIdx.x;
    const int lane = tid & 63, wv = tid >> 6;     // 8 waves
    const int wm = wv >> 2, wn = wv & 3;          // 2 x 4 wave grid
    const int l15 = lane & 15, quad = lane >> 4;

    _Float16* As = sh;           // [3][128*32]
    _Float16* Bs = sh + 12288;   // [3][256*32]

    floatx4 acc[4][4] = {};

    const _Float16* Ag = A + (size_t)(by * 128) * 1024;
    const _Float16* Bg = B + (size_t)(bx * 256) * 1024;

    const int gr  = lane >> 2;                             // row in 16-row window
    const int gcb = ((lane & 3) ^ ((lane >> 3) & 3)) * 8;  // inverse-swizzled src chunk
    const _Float16* agl  = Ag + (size_t)(wv * 16 + gr) * 1024 + gcb;
    const _Float16* bgl0 = Bg + (size_t)(wv * 32 + gr) * 1024 + gcb;
    const _Float16* bgl1 = Bg + (size_t)(wv * 32 + 16 + gr) * 1024 + gcb;
    const int aw  = (wv * 16) * 32;
    const int bw0 = (wv * 32) * 32;
    const int bw1 = (wv * 32 + 16) * 32;

#define STAGE(TT, BB)                                                   \
    {                                                                   \
      load_lds16(agl  + (size_t)(TT) * 32, &As[(BB) * 4096 + aw]);      \
      load_lds16(bgl0 + (size_t)(TT) * 32, &Bs[(BB) * 8192 + bw0]);     \
      load_lds16(bgl1 + (size_t)(TT) * 32, &Bs[(BB) * 8192 + bw1]);     \
    }

    STAGE(0, 0)
    STAGE(1, 1)

    const int rc = ((quad ^ ((l15 >> 1) & 3)) << 3);

#pragma unroll
    for (int t = 0; t < 32; ++t) {
      if (t == 31) { asm volatile("s_waitcnt vmcnt(0)" ::: "memory"); }
      else         { asm volatile("s_waitcnt vmcnt(3)" ::: "memory"); }
      __builtin_amdgcn_s_barrier();
      if (t < 30) {
        const int nb = (t + 2) % 3;
        STAGE(t + 2, nb)
      }
      const int bb = t % 3;
      half8 a[4], b[4];
#pragma unroll
      for (int mt = 0; mt < 4; ++mt)
        a[mt] = *(const half8*)&As[bb * 4096 + (wm * 64 + mt * 16 + l15) * 32 + rc];
#pragma unroll
      for (int nt = 0; nt < 4; ++nt)
        b[nt] = *(const half8*)&Bs[bb * 8192 + (wn * 64 + nt * 16 + l15) * 32 + rc];
      __builtin_amdgcn_s_setprio(1);
#pragma unroll
      for (int mt = 0; mt < 4; ++mt)
#pragma unroll
        for (int nt = 0; nt < 4; ++nt)
          acc[mt][nt] = __builtin_amdgcn_mfma_f32_16x16x32_f16(a[mt], b[nt], acc[mt][nt], 0, 0, 0);
      __builtin_amdgcn_s_setprio(0);
    }
#undef STAGE

    // epilogue: scatter to q16/k16/v16 in (mb, s, dd) layout, + bias, * mask
    const int which = bx >> 2;                 // uniform per CTA (256 | 1024)
    const float* bias = which == 0 ? bq : (which == 1 ? bk : bv);
    _Float16* dst = which == 0 ? q16 : (which == 1 ? k16 : v16);
    const int hh = (bx & 3) * 4 + wn;          // head index, uniform per wave
    const int m2 = hh & 1;
#pragma unroll
    for (int nt = 0; nt < 4; ++nt) {
      const int dd = nt * 16 + l15;
      const float bsv = bias[hh * 64 + dd];
#pragma unroll
      for (int mt = 0; mt < 4; ++mt) {
#pragma unroll
        for (int r = 0; r < 4; ++r) {
          int srow = by * 128 + wm * 64 + mt * 16 + quad * 4 + r;
          int b2 = srow >> 12, s = srow & 4095;
          float mv = 1.f + am[m2 * 4096 + s] * 1e-4f;
          float v = (acc[mt][nt][r] + bsv) * mv;
          int mb = b2 * 16 + hh;
          dst[((size_t)mb * 4096 + s) * 64 + dd] = (_Float16)v;
        }
      }
    }
    return;
  }

  // ================= side GEMM (blocks 768..1023; two 256-thr halves) ===============
  const int half = threadIdx.x >> 8;            // 0 or 1 (wave-aligned split)
  const int stid = threadIdx.x & 255;
  const int sb   = (blockIdx.x - 768) * 2 + half;   // original side block id 0..511
  const int slane = stid & 63, swv = stid >> 6;
  const int kk  = sb >> 8;                      // split-K half
  const int sbb = sb & 255;
  const int sbx = sbb & 31;                     // 0..31 (N/64)
  const int sby = sbb >> 5;                     // 0..7  (M/64)
  const int swm = swv >> 1, swn = swv & 1;
  const int sl15 = slane & 15, squad = slane >> 4;
  _Float16* base = sh + half * 16384;           // 32 KB per half
  _Float16* sAhi = base;
  _Float16* sAlo = base + 4096;
  _Float16* sBhi = base + 8192;
  _Float16* sBlo = base + 12288;

  floatx4 acc[2][2] = {};

  const int srow = slane >> 3;
  const int scol = (((slane & 7) ^ (srow & 7)) * 8);
  const int sswz = sl15 & 7;
  const _Float16* src;
  _Float16* dst;
  if      (swv == 0) { src = Ahi + (size_t)(sby * 64) * 1024; dst = sAhi; }
  else if (swv == 1) { src = Alo + (size_t)(sby * 64) * 1024; dst = sAlo; }
  else if (swv == 2) { src = B   + (size_t)(sbx * 64) * 1024; dst = sBhi; }
  else               { src = Blo + (size_t)(sbx * 64) * 1024; dst = sBlo; }

  const int kbeg = kk * 512;
  for (int k0 = kbeg; k0 < kbeg + 512; k0 += 64) {
    __syncthreads();
#pragma unroll
    for (int i = 0; i < 8; ++i)
      load_lds16(src + (size_t)(i * 8 + srow) * 1024 + k0 + scol, dst + i * 512);
    __syncthreads();
#pragma unroll
    for (int ks = 0; ks < 2; ++ks) {
      const int kc = ks * 4;
      half8 ah[2], al[2], bh[2], bl[2];
#pragma unroll
      for (int mt = 0; mt < 2; ++mt) {
        int off = (swm * 32 + mt * 16 + sl15) * 64 + (((kc + squad) ^ sswz) << 3);
        ah[mt] = *(const half8*)&sAhi[off];
        al[mt] = *(const half8*)&sAlo[off];
      }
#pragma unroll
      for (int nt = 0; nt < 2; ++nt) {
        int off = (swn * 32 + nt * 16 + sl15) * 64 + (((kc + squad) ^ sswz) << 3);
        bh[nt] = *(const half8*)&sBhi[off];
        bl[nt] = *(const half8*)&sBlo[off];
      }
#pragma unroll
      for (int mt = 0; mt < 2; ++mt)
#pragma unroll
        for (int nt = 0; nt < 2; ++nt) {
          acc[mt][nt] = __builtin_amdgcn_mfma_f32_16x16x32_f16(ah[mt], bh[nt], acc[mt][nt], 0, 0, 0);
          acc[mt][nt] = __builtin_amdgcn_mfma_f32_16x16x32_f16(ah[mt], bl[nt], acc[mt][nt], 0, 0, 0);
          acc[mt][nt] = __builtin_amdgcn_mfma_f32_16x16x32_f16(al[mt], bh[nt], acc[mt][nt], 0, 0, 0);
        }
    }
  }
  float* outp = sideQK + (size_t)kk * (512 * 2048);
#pragma unroll
  for (int mt = 0; mt < 2; ++mt)
#pragma unroll
    for (int nt = 0; nt < 2; ++nt)
#pragma unroll
      for (int rr = 0; rr < 4; ++rr) {
        int row = sby * 64 + swm * 32 + mt * 16 + squad * 4 + rr;
        int col = sbx * 64 + swn * 32 + nt * 16 + sl15;
        outp[(size_t)row * 2048 + col] = acc[mt][nt][rr];
      }
}

// ---------------- low-resolution logits + row max | vprep (blocks >= 256) ------------
// vprep writes v16T in (mb, kb, d, s) block-d-major layout: each k_hi V-fragment load
// covers 16 full 64B lines (was 25% line utilization at 8KB lane stride).
__global__ __launch_bounds__(256) void k_lowlogit(const float* __restrict__ sideQK,
                                                  const float* __restrict__ tcv,
                                                  const float* __restrict__ bq,
                                                  const float* __restrict__ bk,
                                                  float* __restrict__ ll,
                                                  float* __restrict__ rmaxout,
                                                  const _Float16* __restrict__ v16,
                                                  float* __restrict__ vhat,
                                                  _Float16* __restrict__ v16T) {
  __shared__ __attribute__((aligned(16))) char shraw[37376];
  const int tid = threadIdx.x;

  if (blockIdx.x >= 256) {
    // ---- vprep: one wave per (mb, blk) ----
    const int lane = tid & 63, wv = tid >> 6;
    _Float16* Vs = (_Float16*)shraw + wv * 2304;   // 32*72
    int bid = (blockIdx.x - 256) * 4 + wv;         // 0..4095
    int mb = bid >> 7, blk = bid & 127;
    const _Float16* src = v16 + ((size_t)mb * 4096 + blk * 32) * 64;
    int r = lane >> 3, c = (lane & 7) * 8;
#pragma unroll
    for (int it = 0; it < 4; ++it)
      *(uint4*)&Vs[(it * 8 + r) * 72 + c] = *(const uint4*)&src[(it * 8 + r) * 64 + c];
    __syncthreads();
    float acc = 0.f;
    half8 col[4];
#pragma unroll
    for (int k = 0; k < 32; ++k) {
      _Float16 x = Vs[k * 72 + lane];
      col[k >> 3][k & 7] = x;
      acc += (float)x;
    }
    vhat[(size_t)bid * 64 + lane] = acc / (tcv[(mb & 1) * 128 + blk] + 1e-6f);
    // (mb, kb, d, s): lane = d owns one contiguous 64B row of 32 k-entries
    _Float16* dst = v16T + ((size_t)(mb * 128 + blk) * 64 + lane) * 32;
#pragma unroll
    for (int p = 0; p < 4; ++p) *(half8*)&dst[p * 8] = col[p];
    return;
  }

  const int mb = blockIdx.x >> 3;
  const int ib = blockIdx.x & 7;       // 0..7 : rows ib*16..+16
  const int b2 = mb >> 4, m2 = mb & 1, hh = mb & 15;
  const int combo = b2 * 2 + m2;
  float* Kh  = (float*)shraw;                     // 128*64
  float* Qh  = (float*)(shraw + 32768);           // 16*64
  float* tcL = (float*)(shraw + 32768 + 4096);    // 128

  const float* P1 = sideQK + (size_t)512 * 2048;

  if (tid < 128) tcL[tid] = tcv[m2 * 128 + tid];
  __syncthreads();
#pragma unroll
  for (int i = 0; i < 8; ++i) {
    int ci = tid + i * 256;
    int row = ci >> 4, c4 = (ci & 15) * 4;
    float tck = tcL[row];
    float den = 1.f / (tck + 1e-6f);
    size_t idx = ((size_t)combo * 128 + row) * 2048 + 1024 + hh * 64 + c4;
    float4 x0 = *(const float4*)&sideQK[idx];
    float4 x1 = *(const float4*)&P1[idx];
    float4 bb = *(const float4*)&bk[hh * 64 + c4];
    float4 o;
    o.x = (x0.x + x1.x + bb.x * tck) * den; o.y = (x0.y + x1.y + bb.y * tck) * den;
    o.z = (x0.z + x1.z + bb.z * tck) * den; o.w = (x0.w + x1.w + bb.w * tck) * den;
    *(float4*)&Kh[row * 64 + c4] = o;
  }
  {
    int row = tid >> 4, c4 = (tid & 15) * 4;
    int gi = ib * 16 + row;
    float tcq = tcL[gi];
    float den = 1.f / (tcq + 1e-6f);
    size_t idx = ((size_t)combo * 128 + gi) * 2048 + hh * 64 + c4;
    float4 x0 = *(const float4*)&sideQK[idx];
    float4 x1 = *(const float4*)&P1[idx];
    float4 bb = *(const float4*)&bq[hh * 64 + c4];
    float4 o;
    o.x = (x0.x + x1.x + bb.x * tcq) * den; o.y = (x0.y + x1.y + bb.y * tcq) * den;
    o.z = (x0.z + x1.z + bb.z * tcq) * den; o.w = (x0.w + x1.w + bb.w * tcq) * den;
    *(float4*)&Qh[row * 64 + c4] = o;
  }
  __syncthreads();

  const int il = tid >> 4, jg = tid & 15;
  const int i = ib * 16 + il;
  float tcq = tcL[i];
  float dots[8] = {};
#pragma unroll
  for (int dd = 0; dd < 16; ++dd) {
    int d4 = ((dd + tid) & 15) * 4;       // lane-rotated: conflict-free LDS columns
    float4 qv = *(const float4*)&Qh[il * 64 + d4];
#pragma unroll
    for (int jj = 0; jj < 8; ++jj) {
      float4 kv = *(const float4*)&Kh[(jg * 8 + jj) * 64 + d4];
      dots[jj] += qv.x * kv.x + qv.y * kv.y + qv.z * kv.z + qv.w * kv.w;
    }
  }
  float tmax = -1e30f;
#pragma unroll
  for (int jj = 0; jj < 8; ++jj) {
    int j = jg * 8 + jj;
    float raw = dots[jj] * 0.125f;
    tmax = fmaxf(tmax, raw);
    float pen = (tcq * tcL[j] < 0.5f) ? 10000.f : 0.f;
    ll[(size_t)mb * 16384 + (size_t)i * 128 + j] = raw - pen;
  }
#pragma unroll
  for (int mk = 1; mk < 16; mk <<= 1) tmax = fmaxf(tmax, __shfl_xor(tmax, mk));
  if (jg == 0) rmaxout[mb * 128 + i] = tmax;
}

// ---------------- exact top-512 threshold + selected-block buckets --------------------
__global__ __launch_bounds__(256) void k_topk(const float* __restrict__ ll,
                                              const float* __restrict__ rmax,
                                              float* __restrict__ thr,
                                              int* __restrict__ selcnt,
                                              int* __restrict__ selkb) {
  const int mb = blockIdx.x;
  const int t = threadIdx.x;
  const int wid = t >> 6;
  __shared__ int red2[2][4];

  unsigned code[64];
#pragma unroll
  for (int j = 0; j < 64; ++j) {
    int e = j * 256 + t;
    int i = e >> 7, jj = e & 127;
    float lrn = ll[(size_t)mb * 16384 + e] - rmax[mb * 128 + i];
    int di = i - jj;
    if (di <= 1 && di >= -1) lrn += 5000.f;
    unsigned b = __float_as_uint(lrn);
    code[j] = (b & 0x80000000u) ? ~b : (b | 0x80000000u);
  }

  unsigned lo = 0u, hi = 0xFFFFFFFFu;
  for (int it = 0; it < 32; ++it) {
    unsigned mid = lo + ((hi - lo) >> 1);
    int c = 0;
#pragma unroll
    for (int j = 0; j < 64; ++j) c += (code[j] >= mid) ? 1 : 0;
#pragma unroll
    for (int mk = 1; mk < 64; mk <<= 1) c += __shfl_xor(c, mk);
    if ((t & 63) == 0) red2[it & 1][wid] = c;
    __syncthreads();
    int total = red2[it & 1][0] + red2[it & 1][1] + red2[it & 1][2] + red2[it & 1][3];
    if (total >= 512) lo = mid; else hi = mid;
  }
  if (t == 0) {
    unsigned bits = (lo & 0x80000000u) ? (lo & 0x7FFFFFFFu) : ~lo;
    thr[mb] = __uint_as_float(bits);
  }
#pragma unroll
  for (int j = 0; j < 64; ++j) {
    if (code[j] >= lo) {
      int e = j * 256 + t;
      int i = e >> 7, jj = e & 127;
      int slot = atomicAdd(&selcnt[mb * 128 + i], 1);
      if (slot < MAXSEL) selkb[(size_t)(mb * 128 + i) * MAXSEL + slot] = jj;
    }
  }
}

// ---------------- hi branch (online softmax, MFMA-norm) + low branch + combine --------
// R7-measured-best (278.2 us): 1 wave per (mb,qb); low branch with 4 independent
// accumulator pairs (breaks the serial accL chain through 128 L2-latency vhat loads);
// v16T (mb,kb,d,s) full-line V loads; list[0..7] register prefetch; single-wave
// lgkmcnt ordering instead of barriers.
__global__ __launch_bounds__(64) void k_hi(const _Float16* __restrict__ q16,
                                           const _Float16* __restrict__ k16,
                                           const _Float16* __restrict__ v16T,
                                           const int* __restrict__ selcnt,
                                           const int* __restrict__ selkb,
                                           const float* __restrict__ rmax,
                                           const float* __restrict__ thr,
                                           const float* __restrict__ tcv,
                                           const float* __restrict__ vhat,
                                           const float* __restrict__ ll,
                                           const float* __restrict__ am,
                                           float* __restrict__ out) {
  const int mb = blockIdx.x & 31, qb = blockIdx.x >> 5;
  const int sid = mb * 128 + qb;
  const int lane = threadIdx.x;
  const int l15 = lane & 15, quad = lane >> 4;
  const int m2 = mb & 1, b2 = mb >> 4, hh = mb & 15;

  __shared__ _Float16 Ps[32 * 40];

  const _Float16* qbase = q16 + ((size_t)mb * 4096 + qb * 32) * 64;
  half8 aq[2][2];
#pragma unroll
  for (int mt = 0; mt < 2; ++mt)
#pragma unroll
    for (int ks = 0; ks < 2; ++ks)
      aq[mt][ks] = *(const half8*)&qbase[(mt * 16 + l15) * 64 + ks * 32 + quad * 8];

  // prefetch selected-block ids 0..7 (list is contiguous, MAXSEL capacity -> safe)
  const int* list = selkb + (size_t)sid * MAXSEL;
  const int4 La = *(const int4*)&list[0];
  const int4 Lb = *(const int4*)&list[4];

  // ---- low branch: 4 independent accumulator pairs (MLP over vhat loads) ----
  const float rmaxb = rmax[sid];
  const float th = thr[mb];
  const float* llrow = ll + (size_t)mb * 16384 + (size_t)qb * 128;
  const float* tcrow = tcv + m2 * 128;
  const float* vhbase = vhat + ((size_t)(mb * 128)) * 64 + lane;
  float a0 = 0.f, a1 = 0.f, a2 = 0.f, a3 = 0.f;
  float n0 = 0.f, n1 = 0.f, n2 = 0.f, n3 = 0.f;
#pragma unroll 2
  for (int j0 = 0; j0 < 128; j0 += 4) {
    float4 l4 = *(const float4*)&llrow[j0];
    float4 t4 = *(const float4*)&tcrow[j0];
    float v0 = vhbase[(size_t)(j0 + 0) * 64];
    float v1 = vhbase[(size_t)(j0 + 1) * 64];
    float v2 = vhbase[(size_t)(j0 + 2) * 64];
    float v3 = vhbase[(size_t)(j0 + 3) * 64];
    int d0 = qb - j0;
    float lr0 = l4.x - rmaxb + ((d0 <= 1 && d0 >= -1) ? 5000.f : 0.f);
    float lr1 = l4.y - rmaxb + ((d0 <= 2 && d0 >= 0) ? 5000.f : 0.f);
    float lr2 = l4.z - rmaxb + ((d0 <= 3 && d0 >= 1) ? 5000.f : 0.f);
    float lr3 = l4.w - rmaxb + ((d0 <= 4 && d0 >= 2) ? 5000.f : 0.f);
    float w0 = (lr0 >= th) ? 0.f : __expf(l4.x - rmaxb) * t4.x;
    float w1 = (lr1 >= th) ? 0.f : __expf(l4.y - rmaxb) * t4.y;
    float w2 = (lr2 >= th) ? 0.f : __expf(l4.z - rmaxb) * t4.z;
    float w3 = (lr3 >= th) ? 0.f : __expf(l4.w - rmaxb) * t4.w;
    a0 += w0 * v0; a1 += w1 * v1; a2 += w2 * v2; a3 += w3 * v3;
    n0 += w0; n1 += w1; n2 += w2; n3 += w3;
  }
  float accL = (a0 + a1) + (a2 + a3);
  float nrmL = (n0 + n1) + (n2 + n3);

  int nk = selcnt[sid];
  if (nk > MAXSEL) nk = MAXSEL;

  const _Float16* kbase  = k16  + (size_t)mb * 4096 * 64;
  const _Float16* vtbase = v16T + (size_t)mb * 128 * 2048;

  float rm[2][4];
  floatx4 o[2][4] = {};
  floatx4 onrm[2] = {};
#pragma unroll
  for (int mt = 0; mt < 2; ++mt)
#pragma unroll
    for (int r = 0; r < 4; ++r) rm[mt][r] = -1e8f;

  half8 ones;
#pragma unroll
  for (int j = 0; j < 8; ++j) ones[j] = (_Float16)1.f;

  for (int t = 0; t < nk; ++t) {
    const int kb = (t < 8) ? sel8(t, La, Lb) : list[t];
    const _Float16* kp = kbase + (size_t)kb * 32 * 64;
    half8 b0[2], b1[2];
#pragma unroll
    for (int ks = 0; ks < 2; ++ks) {
      b0[ks] = *(const half8*)&kp[(l15) * 64 + ks * 32 + quad * 8];
      b1[ks] = *(const half8*)&kp[(16 + l15) * 64 + ks * 32 + quad * 8];
    }
    // V fragments, (mb, kb, d, s) layout: 16 full 64B lines per load instruction
    const _Float16* vp = vtbase + kb * 2048 + quad * 8;
    half8 vb0 = *(const half8*)&vp[(l15) * 32];
    half8 vb1 = *(const half8*)&vp[(16 + l15) * 32];
    half8 vb2 = *(const half8*)&vp[(32 + l15) * 32];
    half8 vb3 = *(const half8*)&vp[(48 + l15) * 32];

    floatx4 sf[2][2] = {};
    sf[0][0] = __builtin_amdgcn_mfma_f32_16x16x32_f16(aq[0][0], b0[0], sf[0][0], 0, 0, 0);
    sf[0][0] = __builtin_amdgcn_mfma_f32_16x16x32_f16(aq[0][1], b0[1], sf[0][0], 0, 0, 0);
    sf[0][1] = __builtin_amdgcn_mfma_f32_16x16x32_f16(aq[0][0], b1[0], sf[0][1], 0, 0, 0);
    sf[0][1] = __builtin_amdgcn_mfma_f32_16x16x32_f16(aq[0][1], b1[1], sf[0][1], 0, 0, 0);
    sf[1][0] = __builtin_amdgcn_mfma_f32_16x16x32_f16(aq[1][0], b0[0], sf[1][0], 0, 0, 0);
    sf[1][0] = __builtin_amdgcn_mfma_f32_16x16x32_f16(aq[1][1], b0[1], sf[1][0], 0, 0, 0);
    sf[1][1] = __builtin_amdgcn_mfma_f32_16x16x32_f16(aq[1][0], b1[0], sf[1][1], 0, 0, 0);
    sf[1][1] = __builtin_amdgcn_mfma_f32_16x16x32_f16(aq[1][1], b1[1], sf[1][1], 0, 0, 0);

    float pen0, pen1;
    {
      float mk0 = 1.f + am[m2 * 4096 + kb * 32 + l15] * 1e-4f;
      float mk1 = 1.f + am[m2 * 4096 + kb * 32 + 16 + l15] * 1e-4f;
      pen0 = 10000.f * (1.f - mk0);
      pen1 = 10000.f * (1.f - mk1);
    }
#pragma unroll
    for (int mt = 0; mt < 2; ++mt)
#pragma unroll
      for (int r = 0; r < 4; ++r) {
        float s0 = sf[mt][0][r] * 0.125f;
        float s1 = sf[mt][1][r] * 0.125f;
        float v = fmaxf(s0, s1);
#pragma unroll
        for (int mk = 1; mk < 16; mk <<= 1) v = fmaxf(v, __shfl_xor(v, mk));
        float mnew  = fmaxf(rm[mt][r], v);
        float alpha = __expf(rm[mt][r] - mnew);
        rm[mt][r] = mnew;
        float p0 = __expf(s0 - mnew - pen0);
        float p1 = __expf(s1 - mnew - pen1);
        o[mt][0][r] *= alpha; o[mt][1][r] *= alpha;
        o[mt][2][r] *= alpha; o[mt][3][r] *= alpha;
        onrm[mt][r] *= alpha;
        int row = mt * 16 + quad * 4 + r;
        Ps[row * 40 + l15] = (_Float16)p0;
        Ps[row * 40 + 16 + l15] = (_Float16)p1;
      }
    // single wave: DS ops are in-order; wait for P writes, then read (no barrier)
    __builtin_amdgcn_sched_barrier(0);
    asm volatile("s_waitcnt lgkmcnt(0)" ::: "memory");
    __builtin_amdgcn_sched_barrier(0);
    half8 pa0 = *(const half8*)&Ps[(l15) * 40 + quad * 8];
    half8 pa1 = *(const half8*)&Ps[(16 + l15) * 40 + quad * 8];
    o[0][0] = __builtin_amdgcn_mfma_f32_16x16x32_f16(pa0, vb0, o[0][0], 0, 0, 0);
    o[0][1] = __builtin_amdgcn_mfma_f32_16x16x32_f16(pa0, vb1, o[0][1], 0, 0, 0);
    o[0][2] = __builtin_amdgcn_mfma_f32_16x16x32_f16(pa0, vb2, o[0][2], 0, 0, 0);
    o[0][3] = __builtin_amdgcn_mfma_f32_16x16x32_f16(pa0, vb3, o[0][3], 0, 0, 0);
    o[1][0] = __builtin_amdgcn_mfma_f32_16x16x32_f16(pa1, vb0, o[1][0], 0, 0, 0);
    o[1][1] = __builtin_amdgcn_mfma_f32_16x16x32_f16(pa1, vb1, o[1][1], 0, 0, 0);
    o[1][2] = __builtin_amdgcn_mfma_f32_16x16x32_f16(pa1, vb2, o[1][2], 0, 0, 0);
    o[1][3] = __builtin_amdgcn_mfma_f32_16x16x32_f16(pa1, vb3, o[1][3], 0, 0, 0);
    onrm[0] = __builtin_amdgcn_mfma_f32_16x16x32_f16(pa0, ones, onrm[0], 0, 0, 0);
    onrm[1] = __builtin_amdgcn_mfma_f32_16x16x32_f16(pa1, ones, onrm[1], 0, 0, 0);
  }

  // ---- combine with low branch and write output ----
  float lo_d[4];
#pragma unroll
  for (int ntd = 0; ntd < 4; ++ntd) lo_d[ntd] = __shfl(accL, ntd * 16 + l15);
#pragma unroll
  for (int mt = 0; mt < 2; ++mt) {
#pragma unroll
    for (int r = 0; r < 4; ++r) {
      int q = mt * 16 + quad * 4 + r;
      int qpos = qb * 32 + q;
      float mq = 1.f + am[m2 * 4096 + qpos] * 1e-4f;
      float logc = (rmaxb - rm[mt][r]) * mq;
      float lc = __expf(fminf(logc, 0.f));
      float hc = __expf(-fmaxf(logc, 0.f));
      float den = onrm[mt][r] * hc + nrmL * lc + 1e-6f;
      float sc = mq / den;
#pragma unroll
      for (int ntd = 0; ntd < 4; ++ntd) {
        float val = (o[mt][ntd][r] * hc + lo_d[ntd] * lc) * sc;
        out[((size_t)b2 * 4096 + qpos) * 1024 + hh * 64 + ntd * 16 + l15] = val;
      }
    }
  }
}

// ---------------- host launch ----------------
extern "C" void kernel_launch(void* const* d_in, const int* in_sizes, int n_in,
                              void* d_out, int out_size, void* d_ws, size_t ws_size,
                              hipStream_t stream) {
  const float* hidden = (const float*)d_in[0];
  const float* am     = (const float*)d_in[1];
  const float* wq     = (const float*)d_in[2];
  const float* bq     = (const float*)d_in[3];
  const float* wk     = (const float*)d_in[4];
  const float* bk     = (const float*)d_in[5];
  const float* wv     = (const float*)d_in[6];
  const float* bv     = (const float*)d_in[7];
  float* out = (float*)d_out;

  char* ws = (char*)d_ws;
  size_t off = 0;
  auto alloc = [&](size_t bytes) -> char* {
    char* p = ws + off;
    off += (bytes + 255) & ~(size_t)255;
    return p;
  };
  _Float16* h16    = (_Float16*)alloc((size_t)M8 * H * 2);      // aliased by v16T later
  _Float16* w16    = (_Float16*)alloc((size_t)N3 * H * 2);
  _Float16* wlo    = (_Float16*)alloc((size_t)2 * H * H * 2);
  _Float16* q16    = (_Float16*)alloc((size_t)MBH * S * DH * 2);
  _Float16* k16    = (_Float16*)alloc((size_t)MBH * S * DH * 2);
  _Float16* v16    = (_Float16*)alloc((size_t)MBH * S * DH * 2);
  _Float16* hb_hi  = (_Float16*)alloc((size_t)4 * NB * H * 2);
  _Float16* hb_lo  = (_Float16*)alloc((size_t)4 * NB * H * 2);
  float* tcv       = (float*)alloc((size_t)2 * NB * 4);
  float* sideQK    = (float*)alloc((size_t)2 * 512 * 2048 * 4);  // 2 split-K partials
  float* ll        = (float*)alloc((size_t)MBH * NB * NB * 4);
  float* rmax      = (float*)alloc((size_t)MBH * NB * 4);
  float* thr       = (float*)alloc((size_t)MBH * 4);
  int*   selcnt    = (int*)alloc((size_t)MBH * NB * 4);
  int*   selkb     = (int*)alloc((size_t)MBH * NB * MAXSEL * 4);
  float* vhat      = (float*)alloc((size_t)MBH * NB * DH * 4);
  _Float16* v16T   = h16;   // h16 dead after k_gemm_qkv; same element count (8.4M)

  k_prep<<<dim3(3328), dim3(256), 0, stream>>>(hidden, am, wq, wk, wv,
                                               h16, w16, wlo, hb_hi, hb_lo, tcv, selcnt);
  // fused: main QKV GEMM (blocks 0..767) + side GEMM (blocks 768..1023)
  k_gemm_qkv<<<dim3(1024), dim3(512), 0, stream>>>(h16, w16, bq, bk, bv, am,
                                                   q16, k16, v16,
                                                   hb_hi, hb_lo, wlo, sideQK);
  // fused: low-res logits (blocks 0..255) + V prep (blocks 256..1279)
  k_lowlogit<<<dim3(1280), dim3(256), 0, stream>>>(sideQK, tcv, bq, bk, ll, rmax,
                                                   v16, vhat, v16T);
  k_topk<<<dim3(32), dim3(256), 0, stream>>>(ll, rmax, thr, selcnt, selkb);
  k_hi<<<dim3(4096), dim3(64), 0, stream>>>(q16, k16, v16T, selcnt, selkb, rmax, thr,
                                            tcv, vhat, ll, am, out);
}